// Round 1
// 318.477 us; speedup vs baseline: 1.0493x; 1.0493x over previous
//
#include <hip/hip_runtime.h>
#include <math.h>

#define N_NODES 50000
#define N_EDGES 600000
#define F 128
#define NT 4
#define KTOT 640               // GEMM K: 128 self + 4*128 per-type means
#define NKTG 20                // K tiles of 32 (640/32)
#define NCT 8                  // out-col tiles of 16 (128/16)
#define N_SEG (NT * N_NODES)   // 200000
#define SCAN_BLK 196           // ceil(N_SEG / 1024)
#define WELEM (NKTG * NCT * 64 * 8)  // 81920 fp16 elements per layer

typedef __attribute__((ext_vector_type(8))) _Float16 f16x8;
typedef __attribute__((ext_vector_type(4))) float f32x4;

__device__ __forceinline__ unsigned short f2h(float f) {
    _Float16 h = (_Float16)f;
    return __builtin_bit_cast(unsigned short, h);
}
__device__ __forceinline__ float h2f(unsigned short u) {
    return (float)__builtin_bit_cast(_Float16, u);
}
__device__ __forceinline__ unsigned pack2h(float a, float b) {
    return (unsigned)f2h(a) | ((unsigned)f2h(b) << 16);
}

// ---- build combined weights B[640,128] per layer, fp16 hi/lo, MFMA-frag order ----
// B rows 0..127  = 0.25 * sum_t Ws[t]   (self, folded type-mean)
// B rows 128+t*128.. = 0.25 * Wn[t]     (neighbor, type t)
__global__ __launch_bounds__(256) void build_w(
    const float* __restrict__ Ws1, const float* __restrict__ Wn1, const float* __restrict__ b1,
    const float* __restrict__ Ws2, const float* __restrict__ Wn2, const float* __restrict__ b2,
    unsigned short* __restrict__ Wh, unsigned short* __restrict__ Wl,
    float* __restrict__ bavg)
{
    int idx = blockIdx.x * 256 + threadIdx.x;
    const int perLayer = NKTG * NCT * 64;   // 10240 fragments
    if (idx < 2 * perLayer) {
        int l = idx >= perLayer;
        int rem = idx - l * perLayer;
        int lane = rem & 63;
        int ct = (rem >> 6) & 7;
        int ktg = (rem >> 6) >> 3;
        const float* Wsl = l ? Ws2 : Ws1;
        const float* Wnl = l ? Wn2 : Wn1;
        unsigned short* oh = Wh + (size_t)l * WELEM + (size_t)rem * 8;
        unsigned short* ol = Wl + (size_t)l * WELEM + (size_t)rem * 8;
        int c = ct * 16 + (lane & 15);
        int kb = ktg * 32 + (lane >> 4) * 8;
#pragma unroll
        for (int j = 0; j < 8; ++j) {
            int k = kb + j;
            float v;
            if (k < F) {
                v = 0.25f * (Wsl[(0 * F + k) * F + c] + Wsl[(1 * F + k) * F + c] +
                             Wsl[(2 * F + k) * F + c] + Wsl[(3 * F + k) * F + c]);
            } else {
                int t = (k - F) >> 7;
                int kk = (k - F) & (F - 1);
                v = 0.25f * Wnl[((size_t)t * F + kk) * F + c];
            }
            _Float16 hh = (_Float16)v;
            oh[j] = __builtin_bit_cast(unsigned short, hh);
            ol[j] = f2h(v - (float)hh);
        }
    } else {
        int k = idx - 2 * perLayer;
        if (k < 2 * F) {
            int l = k >> 7;
            int j = k & (F - 1);
            const float* bl = l ? b2 : b1;
            bavg[k] = 0.25f * (bl[j] + bl[F + j] + bl[2 * F + j] + bl[3 * F + j]);
        }
    }
}

// ---- cast x fp32 -> fp16 (gather source for layer 1 + GEMM A chunk 0) ----
__global__ __launch_bounds__(256) void cast_x(
    const float* __restrict__ x, unsigned short* __restrict__ x16)
{
    int i = blockIdx.x * 256 + threadIdx.x;
    if (i < N_NODES * 64) {
        float2 v = ((const float2*)x)[i];
        ((unsigned*)x16)[i] = pack2h(v.x, v.y);
    }
}

// ---------------- CSR build: seg = dst*4 + t ----------------
__global__ __launch_bounds__(256) void hist_kernel(
    const int* __restrict__ dstA, const int* __restrict__ typA, int* __restrict__ counts)
{
    int e = blockIdx.x * 256 + threadIdx.x;
    if (e < N_EDGES) atomicAdd(&counts[dstA[e] * NT + typA[e]], 1);
}

__global__ __launch_bounds__(256) void scan1(int* __restrict__ counts, int* __restrict__ bsum)
{
    __shared__ int sh[256];
    int t = threadIdx.x;
    int base = blockIdx.x * 1024 + t * 4;
    int v[4];
    int tot = 0;
#pragma unroll
    for (int j = 0; j < 4; ++j) {
        int i = base + j;
        v[j] = (i < N_SEG) ? counts[i] : 0;
        tot += v[j];
    }
    sh[t] = tot;
    __syncthreads();
    for (int ofs = 1; ofs < 256; ofs <<= 1) {
        int add = (t >= ofs) ? sh[t - ofs] : 0;
        __syncthreads();
        sh[t] += add;
        __syncthreads();
    }
    int excl = (t > 0) ? sh[t - 1] : 0;
    if (t == 255) bsum[blockIdx.x] = sh[255];
#pragma unroll
    for (int j = 0; j < 4; ++j) {
        int i = base + j;
        if (i < N_SEG) counts[i] = excl;
        excl += v[j];
    }
}

__global__ __launch_bounds__(256) void scan2(int* __restrict__ bsum)
{
    __shared__ int sh[256];
    int t = threadIdx.x;
    sh[t] = (t < SCAN_BLK) ? bsum[t] : 0;
    __syncthreads();
    for (int ofs = 1; ofs < 256; ofs <<= 1) {
        int add = (t >= ofs) ? sh[t - ofs] : 0;
        __syncthreads();
        sh[t] += add;
        __syncthreads();
    }
    int excl = (t > 0) ? sh[t - 1] : 0;
    if (t < SCAN_BLK) bsum[t] = excl;
}

__global__ __launch_bounds__(256) void scan3(
    int* __restrict__ counts, const int* __restrict__ bsum, int* __restrict__ cursor)
{
    int i = blockIdx.x * 256 + threadIdx.x;
    if (i < N_SEG) {
        int v = counts[i] + bsum[i >> 10];
        counts[i] = v;
        cursor[i] = v;
    }
    if (i == 0) counts[N_SEG] = N_EDGES;   // sentinel: end of last segment
}

// permute: bucket-sorted edge list; payload = (src << 2) | type
__global__ __launch_bounds__(256) void permute_kernel(
    const int* __restrict__ srcA, const int* __restrict__ dstA, const int* __restrict__ typA,
    int* __restrict__ cursor, unsigned* __restrict__ perm)
{
    int e = blockIdx.x * 256 + threadIdx.x;
    if (e < N_EDGES) {
        int t = typA[e];
        int seg = dstA[e] * NT + t;
        int pos = atomicAdd(&cursor[seg], 1);
        perm[pos] = ((unsigned)srcA[e] << 2) | (unsigned)t;
    }
}

// ---- aggregate: per node, per-type mean of H[src] rows -> Agg[N,512] fp16 ----
// one wave per node; 16-deep load pipeline; scalar (uniform) type dispatch
__global__ __launch_bounds__(256) void aggregate(
    const unsigned short* __restrict__ H,     // [N,128] fp16
    const unsigned* __restrict__ perm,
    const int* __restrict__ off,              // seg starts, +sentinel at [N_SEG]
    unsigned short* __restrict__ Agg)         // [N,512] fp16
{
    int node = blockIdx.x * 4 + (threadIdx.x >> 6);
    int lane = threadIdx.x & 63;
    if (node >= N_NODES) return;

    int o0 = off[node * NT + 0];
    int o1 = off[node * NT + 1];
    int o2 = off[node * NT + 2];
    int o3 = off[node * NT + 3];
    int oe = off[node * NT + 4];   // sentinel-safe for last node

    const unsigned* H32 = (const unsigned*)H;
    float ax0 = 0.f, ay0 = 0.f, ax1 = 0.f, ay1 = 0.f;
    float ax2 = 0.f, ay2 = 0.f, ax3 = 0.f, ay3 = 0.f;

    for (int b = o0; b < oe; b += 16) {
        int pidx = b + (lane & 15);
        unsigned pk = perm[pidx < oe ? pidx : oe - 1];
        int nb = oe - b;                       // wave-uniform
        int us[16];
        unsigned uv[16];
#pragma unroll
        for (int i = 0; i < 16; ++i) {
            if (i < nb) {
                us[i] = __builtin_amdgcn_readlane((int)pk, i);   // uniform (SGPR)
                uv[i] = H32[(size_t)((unsigned)us[i] >> 2) * 64 + lane];
            }
        }
#pragma unroll
        for (int i = 0; i < 16; ++i) {
            if (i < nb) {
                float fx = h2f((unsigned short)(uv[i] & 0xffffu));
                float fy = h2f((unsigned short)(uv[i] >> 16));
                int t = us[i] & 3;             // uniform -> scalar branch
                if (t == 0)      { ax0 += fx; ay0 += fy; }
                else if (t == 1) { ax1 += fx; ay1 += fy; }
                else if (t == 2) { ax2 += fx; ay2 += fy; }
                else             { ax3 += fx; ay3 += fy; }
            }
        }
    }

    float i0 = 1.f / fmaxf((float)(o1 - o0), 1.f);
    float i1 = 1.f / fmaxf((float)(o2 - o1), 1.f);
    float i2 = 1.f / fmaxf((float)(o3 - o2), 1.f);
    float i3 = 1.f / fmaxf((float)(oe - o3), 1.f);

    unsigned* A32 = (unsigned*)Agg + (size_t)node * 256 + lane;
    A32[0]   = pack2h(ax0 * i0, ay0 * i0);
    A32[64]  = pack2h(ax1 * i1, ay1 * i1);
    A32[128] = pack2h(ax2 * i2, ay2 * i2);
    A32[192] = pack2h(ax3 * i3, ay3 * i3);
}

// ---- fused GEMM: out[N,128] = [H | Agg][N,640] @ B[640,128] (+bias, epilogue) ----
// block = 64 rows x 128 cols; 4 waves, each 32 cols; K staged in 5 chunks of 128
__global__ __launch_bounds__(256) void gemm_fused(
    const unsigned short* __restrict__ Hin,   // [N,128] fp16
    const unsigned short* __restrict__ Agg,   // [N,512] fp16
    const unsigned short* __restrict__ Wh,    // frag-ordered fp16 hi (this layer)
    const unsigned short* __restrict__ Wl,    // frag-ordered fp16 lo
    const float* __restrict__ bias,           // 128 fp32
    float* __restrict__ outF,                 // fp32 output (layer 2)
    unsigned short* __restrict__ outH,        // fp16 output (layer 1, norm+relu)
    int doNormRelu)
{
    __shared__ unsigned short AS[64][136];    // fp16 A chunk, padded pitch
    __shared__ float rs[64][4];               // row sumsq partials (L1 epilogue)

    const int tid = threadIdx.x;
    const int lane = tid & 63;
    const int w = tid >> 6;
    const int quad = lane >> 4;
    const int l15 = lane & 15;
    const int nodeBase = blockIdx.x * 64;

    f32x4 acc[4][2];
#pragma unroll
    for (int rt = 0; rt < 4; ++rt)
#pragma unroll
        for (int ci = 0; ci < 2; ++ci)
            acc[rt][ci] = (f32x4){0.f, 0.f, 0.f, 0.f};

    const f16x8* BH = (const f16x8*)Wh;
    const f16x8* BL = (const f16x8*)Wl;

    const int r = tid >> 2;
    const int cb = (tid & 3) * 32;
    {
        int n = nodeBase + r;
        int nc = n < N_NODES ? n : N_NODES - 1;

        for (int kc = 0; kc < 5; ++kc) {
            const unsigned short* src = (kc == 0)
                ? (Hin + (size_t)nc * F + cb)
                : (Agg + (size_t)nc * 512 + (size_t)(kc - 1) * F + cb);
            uint4 v0 = *(const uint4*)(src);
            uint4 v1 = *(const uint4*)(src + 8);
            uint4 v2 = *(const uint4*)(src + 16);
            uint4 v3 = *(const uint4*)(src + 24);

            __syncthreads();                   // prev chunk's reads done
            *(uint4*)&AS[r][cb]      = v0;
            *(uint4*)&AS[r][cb + 8]  = v1;
            *(uint4*)&AS[r][cb + 16] = v2;
            *(uint4*)&AS[r][cb + 24] = v3;
            __syncthreads();                   // chunk staged

#pragma unroll
            for (int kt = 0; kt < 4; ++kt) {
                int ktg = kc * 4 + kt;
                f16x8 bh[2], bl[2];
#pragma unroll
                for (int ci = 0; ci < 2; ++ci) {
                    int fi = (ktg * NCT + (w * 2 + ci)) * 64 + lane;
                    bh[ci] = BH[fi];
                    bl[ci] = BL[fi];
                }
                f16x8 ah[4];
#pragma unroll
                for (int rt = 0; rt < 4; ++rt)
                    ah[rt] = *(const f16x8*)&AS[rt * 16 + l15][kt * 32 + quad * 8];
#pragma unroll
                for (int rt = 0; rt < 4; ++rt)
#pragma unroll
                    for (int ci = 0; ci < 2; ++ci) {
                        acc[rt][ci] = __builtin_amdgcn_mfma_f32_16x16x32_f16(ah[rt], bh[ci], acc[rt][ci], 0, 0, 0);
                        acc[rt][ci] = __builtin_amdgcn_mfma_f32_16x16x32_f16(ah[rt], bl[ci], acc[rt][ci], 0, 0, 0);
                    }
            }
        }
    }

    float bv0 = bias[w * 32 + l15];
    float bv1 = bias[w * 32 + 16 + l15];

    if (doNormRelu) {
        // row L2-norm across 128 cols: intra-wave 16-lane reduce + cross-wave LDS
#pragma unroll
        for (int rt = 0; rt < 4; ++rt)
#pragma unroll
            for (int rr = 0; rr < 4; ++rr) {
                float vx = acc[rt][0][rr] + bv0;
                float vy = acc[rt][1][rr] + bv1;
                float s = vx * vx + vy * vy;
                s += __shfl_xor(s, 1);
                s += __shfl_xor(s, 2);
                s += __shfl_xor(s, 4);
                s += __shfl_xor(s, 8);
                if (l15 == 0) rs[rt * 16 + quad * 4 + rr][w] = s;
            }
        __syncthreads();
#pragma unroll
        for (int rt = 0; rt < 4; ++rt)
#pragma unroll
            for (int rr = 0; rr < 4; ++rr) {
                int row = rt * 16 + quad * 4 + rr;
                int nn = nodeBase + row;
                if (nn < N_NODES) {
                    float tot = rs[row][0] + rs[row][1] + rs[row][2] + rs[row][3];
                    float sc = 1.0f / fmaxf(sqrtf(tot), 1e-12f);
                    float vx = fmaxf((acc[rt][0][rr] + bv0) * sc, 0.f);
                    float vy = fmaxf((acc[rt][1][rr] + bv1) * sc, 0.f);
                    outH[(size_t)nn * F + w * 32 + l15]      = f2h(vx);
                    outH[(size_t)nn * F + w * 32 + 16 + l15] = f2h(vy);
                }
            }
    } else {
#pragma unroll
        for (int rt = 0; rt < 4; ++rt)
#pragma unroll
            for (int rr = 0; rr < 4; ++rr) {
                int nn = nodeBase + rt * 16 + quad * 4 + rr;
                if (nn < N_NODES) {
                    float* o = outF + (size_t)nn * F + w * 32 + l15;
                    o[0]  = acc[rt][0][rr] + bv0;
                    o[16] = acc[rt][1][rr] + bv1;
                }
            }
    }
}

extern "C" void kernel_launch(void* const* d_in, const int* in_sizes, int n_in,
                              void* d_out, int out_size, void* d_ws, size_t ws_size,
                              hipStream_t stream)
{
    const float* x   = (const float*)d_in[0];
    const float* Ws1 = (const float*)d_in[1];
    const float* Wn1 = (const float*)d_in[2];
    const float* b1  = (const float*)d_in[3];
    const float* Ws2 = (const float*)d_in[4];
    const float* Wn2 = (const float*)d_in[5];
    const float* b2  = (const float*)d_in[6];
    const int* edge_index = (const int*)d_in[7];
    const int* edge_type  = (const int*)d_in[8];

    const int* srcA = edge_index;
    const int* dstA = edge_index + N_EDGES;

    // workspace layout (all 4B-aligned)
    unsigned short* x16 = (unsigned short*)d_ws;             // N*128 u16 = 12.8 MB
    unsigned short* h1  = x16 + (size_t)N_NODES * F;         // N*128 u16 = 12.8 MB
    unsigned short* agg = h1 + (size_t)N_NODES * F;          // N*512 u16 = 51.2 MB
    unsigned short* Wh  = agg + (size_t)N_NODES * 512;       // 2*WELEM u16
    unsigned short* Wl  = Wh + (size_t)2 * WELEM;            // 2*WELEM u16
    float* bavg = (float*)(Wl + (size_t)2 * WELEM);          // 256 f32
    int* counts = (int*)(bavg + 2 * F);                      // N_SEG + 2 (off + sentinel)
    int* cursor = counts + (N_SEG + 2);                      // N_SEG
    int* bsum   = cursor + N_SEG;                            // 256
    unsigned* perm = (unsigned*)(bsum + 256);                // N_EDGES u32 = 2.4 MB
    int* off = counts;                                       // alias after scan3

    // weights + bias + fp16 cast of x
    hipLaunchKernelGGL(build_w, dim3(81), dim3(256), 0, stream,
                       Ws1, Wn1, b1, Ws2, Wn2, b2, Wh, Wl, bavg);
    hipLaunchKernelGGL(cast_x, dim3((N_NODES * 64 + 255) / 256), dim3(256), 0, stream,
                       x, x16);

    // CSR build (shared by both layers)
    hipMemsetAsync(counts, 0, (size_t)N_SEG * sizeof(int), stream);
    hipLaunchKernelGGL(hist_kernel, dim3((N_EDGES + 255) / 256), dim3(256), 0, stream,
                       dstA, edge_type, counts);
    hipLaunchKernelGGL(scan1, dim3(SCAN_BLK), dim3(256), 0, stream, counts, bsum);
    hipLaunchKernelGGL(scan2, dim3(1), dim3(256), 0, stream, bsum);
    hipLaunchKernelGGL(scan3, dim3((N_SEG + 255) / 256), dim3(256), 0, stream,
                       counts, bsum, cursor);
    hipLaunchKernelGGL(permute_kernel, dim3((N_EDGES + 255) / 256), dim3(256), 0, stream,
                       srcA, dstA, edge_type, cursor, perm);

    const int gemmGrid = (N_NODES + 63) / 64;     // 782
    const int aggGrid  = (N_NODES + 3) / 4;       // 12500

    // ---------- layer 1 ----------
    hipLaunchKernelGGL(aggregate, dim3(aggGrid), dim3(256), 0, stream,
                       x16, perm, off, agg);
    hipLaunchKernelGGL(gemm_fused, dim3(gemmGrid), dim3(256), 0, stream,
                       x16, agg, Wh, Wl, bavg, (float*)nullptr, h1, 1);

    // ---------- layer 2 ----------
    hipLaunchKernelGGL(aggregate, dim3(aggGrid), dim3(256), 0, stream,
                       h1, perm, off, agg);
    hipLaunchKernelGGL(gemm_fused, dim3(gemmGrid), dim3(256), 0, stream,
                       h1, agg, Wh + WELEM, Wl + WELEM, bavg + F, (float*)d_out,
                       (unsigned short*)nullptr, 0);
}